// Round 1
// 448.173 us; speedup vs baseline: 1.0070x; 1.0070x over previous
//
#include <hip/hip_runtime.h>
#include <hip/hip_bf16.h>
#include <math.h>

// Problem constants:
//   B=4, Lq=4096, C=768, NH=12, d=64, NP=4, nl=1, H=W=64, Lin=4096, hid=192
#define B_    4
#define LQ    4096
#define CC    768
#define NH_   12
#define DH    64
#define NP_   4
#define HH    64
#define WW    64
#define HID   192
#define ROWS  (B_ * LQ)          // 16384
#define EPS_  1e-5f

typedef __bf16 bf16x8 __attribute__((ext_vector_type(8)));
typedef __bf16 bf16x4 __attribute__((ext_vector_type(4)));
typedef float  f32x4  __attribute__((ext_vector_type(4)));

typedef __attribute__((address_space(3))) void* lds_vp;
typedef const __attribute__((address_space(1))) void* gbl_vp;

// ---------------------------------------------------------------------------
// Batched weight prep: f32 [K,N] -> bf16 [Npad,K] transposed; rows [N,Npad) zero
// ---------------------------------------------------------------------------
struct PrepJob { const float* W; __bf16* Wt; int K; int N; int Npad; };
struct PrepJobs { PrepJob j[6]; };

__global__ __launch_bounds__(256)
void prep_all(PrepJobs jobs) {
    PrepJob job = jobs.j[blockIdx.z];
    int k0 = blockIdx.x * 64, n0 = blockIdx.y * 64;
    if (k0 >= job.K || n0 >= job.Npad) return;
    __shared__ float tile[64][65];
    int c = threadIdx.x & 63, r0 = threadIdx.x >> 6;
    #pragma unroll
    for (int i = 0; i < 16; ++i) {
        int kk = i * 4 + r0;
        float v = 0.f;
        if (k0 + kk < job.K && n0 + c < job.N) v = job.W[(size_t)(k0 + kk) * job.N + n0 + c];
        tile[kk][c] = v;
    }
    __syncthreads();
    #pragma unroll
    for (int i = 0; i < 16; ++i) {
        int nn = i * 4 + r0;
        if (n0 + nn < job.Npad && k0 + c < job.K)
            job.Wt[(size_t)(n0 + nn) * job.K + k0 + c] = (__bf16)tile[c][nn];
    }
}

// ---------------------------------------------------------------------------
// Reductions
// ---------------------------------------------------------------------------
__inline__ __device__ float wave_sum64(float v) {
    #pragma unroll
    for (int o = 32; o > 0; o >>= 1) v += __shfl_down(v, o, 64);
    return v;
}

// ---------------------------------------------------------------------------
// Fused dual LayerNorm (f32 in, bf16 out), float4 vectorized.
// blockIdx.y selects stream 0 (query) or 1 (feat). 256 thr, 192 active vec4.
// ---------------------------------------------------------------------------
__global__ __launch_bounds__(256)
void ln2_kernel(const float* __restrict__ x0, const float* __restrict__ g0,
                const float* __restrict__ b0, __bf16* __restrict__ y0,
                const float* __restrict__ x1, const float* __restrict__ g1,
                const float* __restrict__ b1, __bf16* __restrict__ y1) {
    int sel = blockIdx.y;
    const float* x = sel ? x1 : x0;
    const float* g = sel ? g1 : g0;
    const float* b = sel ? b1 : b0;
    __bf16* y = sel ? y1 : y0;
    int row = blockIdx.x;
    const float* xr = x + (size_t)row * CC;
    __bf16* yr = y + (size_t)row * CC;
    int t = threadIdx.x;
    f32x4 xv = {0.f, 0.f, 0.f, 0.f};
    if (t < 192) xv = *(const f32x4*)(xr + t * 4);
    float s  = xv[0] + xv[1] + xv[2] + xv[3];
    float s2 = xv[0]*xv[0] + xv[1]*xv[1] + xv[2]*xv[2] + xv[3]*xv[3];
    __shared__ float red[8];
    float ws = wave_sum64(s), ws2 = wave_sum64(s2);
    int w = t >> 6;
    if ((t & 63) == 0) { red[w] = ws; red[4 + w] = ws2; }
    __syncthreads();
    float S  = red[0] + red[1] + red[2] + red[3];
    float S2 = red[4] + red[5] + red[6] + red[7];
    float mean = S / CC;
    float inv  = rsqrtf(S2 / CC - mean * mean + EPS_);
    if (t < 192) {
        f32x4 gv = *(const f32x4*)(g + t * 4);
        f32x4 bv = *(const f32x4*)(b + t * 4);
        bf16x4 o;
        #pragma unroll
        for (int e = 0; e < 4; ++e)
            o[e] = (__bf16)((xv[e] - mean) * inv * gv[e] + bv[e]);
        *(bf16x4*)(yr + t * 4) = o;
    }
}

// ---------------------------------------------------------------------------
// LayerNorm, bf16 in -> bf16 out, bf16x8 vectorized (96 active threads of 256)
// ---------------------------------------------------------------------------
__global__ __launch_bounds__(256)
void ln_bf_kernel(const __bf16* __restrict__ x, const float* __restrict__ g,
                  const float* __restrict__ b, __bf16* __restrict__ y) {
    int row = blockIdx.x;
    const __bf16* xr = x + (size_t)row * CC;
    __bf16* yr = y + (size_t)row * CC;
    int t = threadIdx.x;
    float xv[8]; bf16x8 raw = {};
    if (t < 96) raw = *(const bf16x8*)(xr + t * 8);
    float s = 0.f, s2 = 0.f;
    #pragma unroll
    for (int e = 0; e < 8; ++e) { xv[e] = (float)raw[e]; s += xv[e]; s2 += xv[e]*xv[e]; }
    __shared__ float red[8];
    float ws = wave_sum64(s), ws2 = wave_sum64(s2);
    int w = t >> 6;
    if ((t & 63) == 0) { red[w] = ws; red[4 + w] = ws2; }
    __syncthreads();
    float S  = red[0] + red[1] + red[2] + red[3];
    float S2 = red[4] + red[5] + red[6] + red[7];
    float mean = S / CC;
    float inv  = rsqrtf(S2 / CC - mean * mean + EPS_);
    if (t < 96) {
        bf16x8 o;
        #pragma unroll
        for (int e = 0; e < 8; ++e)
            o[e] = (__bf16)((xv[e] - mean) * inv * g[t * 8 + e] + b[t * 8 + e]);
        *(bf16x8*)(yr + t * 8) = o;
    }
}

// ---------------------------------------------------------------------------
// bf16 MFMA GEMM, 128x128 tile, 2-phase pipelined (double-buffered LDS,
// prefetch next K-tile before compute, ONE barrier per K-step).
// flags: 1 gelu, 2 out bf16, 4 res bf16
// ---------------------------------------------------------------------------
__global__ __launch_bounds__(256)
void gemm_bt(const __bf16* __restrict__ A, const __bf16* __restrict__ Bt,
             const float* __restrict__ ba, int Nsplit, const float* __restrict__ bb,
             const void* __restrict__ res, void* __restrict__ out,
             int M, int K, int N, int flags) {
    __shared__ __bf16 As[2][128 * 32];
    __shared__ __bf16 Bs[2][128 * 32];

    int t = threadIdx.x;
    int lane = t & 63, wave = t >> 6;
    int bm = blockIdx.y * 128, bn = blockIdx.x * 128;
    int wm = wave & 1, wn = wave >> 1;

    f32x4 acc[4][4] = {};

    int row0 = t >> 2,           kc0 = (t & 3) ^ ((row0 >> 1) & 3);
    int row1 = (256 + t) >> 2,   kc1 = ((256 + t) & 3) ^ ((row1 >> 1) & 3);

    const __bf16* a0 = A  + (size_t)(bm + row0) * K + kc0 * 8;
    const __bf16* a1 = A  + (size_t)(bm + row1) * K + kc1 * 8;
    const __bf16* b0 = Bt + (size_t)(bn + row0) * K + kc0 * 8;
    const __bf16* b1 = Bt + (size_t)(bn + row1) * K + kc1 * 8;

    int rbase = wm * 64 + (lane & 15);
    int nbase = wn * 64 + (lane & 15);
    int kq = lane >> 4;

    // prologue: stage K-tile 0 into buffer 0; syncthreads drains vmcnt(0)
    __builtin_amdgcn_global_load_lds((gbl_vp)(a0), (lds_vp)&As[0][t * 8], 16, 0, 0);
    __builtin_amdgcn_global_load_lds((gbl_vp)(a1), (lds_vp)&As[0][(256 + t) * 8], 16, 0, 0);
    __builtin_amdgcn_global_load_lds((gbl_vp)(b0), (lds_vp)&Bs[0][t * 8], 16, 0, 0);
    __builtin_amdgcn_global_load_lds((gbl_vp)(b1), (lds_vp)&Bs[0][(256 + t) * 8], 16, 0, 0);
    __syncthreads();

    int cur = 0;
    for (int k0 = 0; k0 < K; k0 += 32) {
        int nxt = cur ^ 1;
        // issue next tile's loads FIRST — latency hides under the MFMA below
        if (k0 + 32 < K) {
            __builtin_amdgcn_global_load_lds((gbl_vp)(a0 + k0 + 32), (lds_vp)&As[nxt][t * 8], 16, 0, 0);
            __builtin_amdgcn_global_load_lds((gbl_vp)(a1 + k0 + 32), (lds_vp)&As[nxt][(256 + t) * 8], 16, 0, 0);
            __builtin_amdgcn_global_load_lds((gbl_vp)(b0 + k0 + 32), (lds_vp)&Bs[nxt][t * 8], 16, 0, 0);
            __builtin_amdgcn_global_load_lds((gbl_vp)(b1 + k0 + 32), (lds_vp)&Bs[nxt][(256 + t) * 8], 16, 0, 0);
        }

        bf16x8 afr[4], bfr[4];
        #pragma unroll
        for (int i = 0; i < 4; ++i) {
            int r = rbase + i * 16;
            afr[i] = *(const bf16x8*)&As[cur][r * 32 + ((kq ^ ((r >> 1) & 3)) * 8)];
        }
        #pragma unroll
        for (int j = 0; j < 4; ++j) {
            int n = nbase + j * 16;
            bfr[j] = *(const bf16x8*)&Bs[cur][n * 32 + ((kq ^ ((n >> 1) & 3)) * 8)];
        }
        #pragma unroll
        for (int i = 0; i < 4; ++i)
            #pragma unroll
            for (int j = 0; j < 4; ++j)
                acc[i][j] = __builtin_amdgcn_mfma_f32_16x16x32_bf16(afr[i], bfr[j], acc[i][j], 0, 0, 0);

        // single barrier per K-step: drains vmcnt(0) (prefetch done) + lgkm
        __syncthreads();
        cur = nxt;
    }

    int rowq = lane >> 4;
    int colj[4]; float biasj[4];
    #pragma unroll
    for (int j = 0; j < 4; ++j) {
        int c = bn + wn * 64 + j * 16 + (lane & 15);
        colj[j] = c;
        biasj[j] = (c < N) ? ((c < Nsplit) ? ba[c] : bb[c - Nsplit]) : 0.f;
    }
    int do_gelu = flags & 1, out_bf = flags & 2, res_bf = flags & 4;
    #pragma unroll
    for (int i = 0; i < 4; ++i) {
        #pragma unroll
        for (int r = 0; r < 4; ++r) {
            int m = bm + wm * 64 + i * 16 + rowq * 4 + r;
            #pragma unroll
            for (int j = 0; j < 4; ++j) {
                if (colj[j] < N) {
                    float v = acc[i][j][r] + biasj[j];
                    if (do_gelu) v = 0.5f * v * (1.f + erff(v * 0.70710678118f));
                    size_t oi = (size_t)m * N + colj[j];
                    if (res) v += res_bf ? (float)((const __bf16*)res)[oi]
                                         : ((const float*)res)[oi];
                    if (out_bf) ((__bf16*)out)[oi] = (__bf16)v;
                    else        ((float*)out)[oi]  = v;
                }
            }
        }
    }
}

// ---------------------------------------------------------------------------
// 64x64-tile GEMM for small N (144/192), 2-phase pipelined like gemm_bt.
// Grid: (Npad/64, M/64). flags: 1 gelu, 2 out bf16
// ---------------------------------------------------------------------------
__global__ __launch_bounds__(256)
void gemm_bt64(const __bf16* __restrict__ A, const __bf16* __restrict__ Bt,
               const float* __restrict__ ba, int Nsplit, const float* __restrict__ bb,
               void* __restrict__ out, int M, int K, int N, int flags) {
    __shared__ __bf16 As[2][64 * 32];
    __shared__ __bf16 Bs[2][64 * 32];

    int t = threadIdx.x;
    int lane = t & 63, wave = t >> 6;
    int bm = blockIdx.y * 64, bn = blockIdx.x * 64;

    f32x4 acc[4] = {};

    int row0 = t >> 2, kc0 = (t & 3) ^ ((row0 >> 1) & 3);
    const __bf16* a0 = A  + (size_t)(bm + row0) * K + kc0 * 8;
    const __bf16* b0 = Bt + (size_t)(bn + row0) * K + kc0 * 8;

    int rbase = wave * 16 + (lane & 15);
    int nbase = lane & 15;
    int kq = lane >> 4;

    __builtin_amdgcn_global_load_lds((gbl_vp)(a0), (lds_vp)&As[0][t * 8], 16, 0, 0);
    __builtin_amdgcn_global_load_lds((gbl_vp)(b0), (lds_vp)&Bs[0][t * 8], 16, 0, 0);
    __syncthreads();

    int cur = 0;
    for (int k0 = 0; k0 < K; k0 += 32) {
        int nxt = cur ^ 1;
        if (k0 + 32 < K) {
            __builtin_amdgcn_global_load_lds((gbl_vp)(a0 + k0 + 32), (lds_vp)&As[nxt][t * 8], 16, 0, 0);
            __builtin_amdgcn_global_load_lds((gbl_vp)(b0 + k0 + 32), (lds_vp)&Bs[nxt][t * 8], 16, 0, 0);
        }

        bf16x8 afr = *(const bf16x8*)&As[cur][rbase * 32 + ((kq ^ ((rbase >> 1) & 3)) * 8)];
        #pragma unroll
        for (int j = 0; j < 4; ++j) {
            int n = nbase + j * 16;
            bf16x8 bfr = *(const bf16x8*)&Bs[cur][n * 32 + ((kq ^ ((n >> 1) & 3)) * 8)];
            acc[j] = __builtin_amdgcn_mfma_f32_16x16x32_bf16(afr, bfr, acc[j], 0, 0, 0);
        }

        __syncthreads();
        cur = nxt;
    }

    int rowq = lane >> 4;
    int do_gelu = flags & 1, out_bf = flags & 2;
    #pragma unroll
    for (int r = 0; r < 4; ++r) {
        int m = bm + wave * 16 + rowq * 4 + r;
        #pragma unroll
        for (int j = 0; j < 4; ++j) {
            int c = bn + j * 16 + (lane & 15);
            if (c < N) {
                float v = acc[j][r] + ((c < Nsplit) ? ba[c] : bb[c - Nsplit]);
                if (do_gelu) v = 0.5f * v * (1.f + erff(v * 0.70710678118f));
                size_t oi = (size_t)m * N + c;
                if (out_bf) ((__bf16*)out)[oi] = (__bf16)v;
                else        ((float*)out)[oi]  = v;
            }
        }
    }
}

// ---------------------------------------------------------------------------
// Deformable sampling v3: one wave per (b,q,h).
//   lane = p*16 + g : p = sample point (0..3), g = channel group (4 bf16).
// Each lane: one coord chain, 4 in-lane corner loads (constant cx/cy).
// Butterfly (xor 16,32) sums points; lanes p==0 store bf16x4.
// ---------------------------------------------------------------------------
__global__ __launch_bounds__(256)
void sample_kernel(const __bf16* __restrict__ value, const float* __restrict__ offatt,
                   const float* __restrict__ refp, __bf16* __restrict__ out) {
    int wid  = blockIdx.x * 4 + (threadIdx.x >> 6);
    int lane = threadIdx.x & 63;
    int h  = wid % NH_;
    int bq = wid / NH_;
    int b  = bq / LQ;

    const float* oa = offatt + (size_t)bq * 144;
    float rx = refp[(size_t)bq * 2 + 0] * (float)WW - 0.5f;
    float ry = refp[(size_t)bq * 2 + 1] * (float)HH - 0.5f;

    // softmax over this head's 4 logits (wave-uniform -> s_loads)
    float l0 = oa[96 + h * 4 + 0], l1 = oa[96 + h * 4 + 1];
    float l2 = oa[96 + h * 4 + 2], l3 = oa[96 + h * 4 + 3];
    float mx = fmaxf(fmaxf(l0, l1), fmaxf(l2, l3));
    float e0 = __expf(l0 - mx), e1 = __expf(l1 - mx);
    float e2 = __expf(l2 - mx), e3 = __expf(l3 - mx);
    float rs = 1.f / (e0 + e1 + e2 + e3);

    int pp = lane >> 4;       // point id
    int g  = lane & 15;       // channel group
    float wpl = (pp == 0) ? e0 : (pp == 1) ? e1 : (pp == 2) ? e2 : e3;
    wpl *= rs;

    // per-lane point coords (8B vector load, divergent by pp)
    const float* oxy = oa + h * 8 + pp * 2;
    float x = rx + oxy[0];
    float y = ry + oxy[1];
    float x0f = floorf(x), y0f = floorf(y);
    float wx1 = x - x0f, wy1 = y - y0f;
    float wx0 = 1.f - wx1, wy0 = 1.f - wy1;
    int x0 = (int)x0f, y0 = (int)y0f;
    int x1 = x0 + 1, y1 = y0 + 1;
    // zero weights at OOB; address clamp via &63 (weight already 0 there)
    float mx0 = ((unsigned)x0 < (unsigned)WW) ? wx0 : 0.f;
    float mx1 = ((unsigned)x1 < (unsigned)WW) ? wx1 : 0.f;
    float my0 = (((unsigned)y0 < (unsigned)HH) ? wy0 : 0.f) * wpl;
    float my1 = (((unsigned)y1 < (unsigned)HH) ? wy1 : 0.f) * wpl;
    int xc0 = x0 & (WW - 1), xc1 = x1 & (WW - 1);
    int r0 = (y0 & (HH - 1)) << 6, r1 = (y1 & (HH - 1)) << 6;

    const __bf16* vbase = value + (size_t)b * (LQ * CC) + h * DH + g * 4;
    bf16x4 v00 = *(const bf16x4*)(vbase + (size_t)(r0 + xc0) * CC);
    bf16x4 v01 = *(const bf16x4*)(vbase + (size_t)(r0 + xc1) * CC);
    bf16x4 v10 = *(const bf16x4*)(vbase + (size_t)(r1 + xc0) * CC);
    bf16x4 v11 = *(const bf16x4*)(vbase + (size_t)(r1 + xc1) * CC);
    float w00 = mx0 * my0, w01 = mx1 * my0, w10 = mx0 * my1, w11 = mx1 * my1;

    f32x4 acc;
    #pragma unroll
    for (int e = 0; e < 4; ++e)
        acc[e] = w00 * (float)v00[e] + w01 * (float)v01[e]
               + w10 * (float)v10[e] + w11 * (float)v11[e];

    #pragma unroll
    for (int e = 0; e < 4; ++e) {
        acc[e] += __shfl_xor(acc[e], 16, 64);
        acc[e] += __shfl_xor(acc[e], 32, 64);
    }
    if (pp == 0) {
        bf16x4 o;
        o[0] = (__bf16)acc[0]; o[1] = (__bf16)acc[1];
        o[2] = (__bf16)acc[2]; o[3] = (__bf16)acc[3];
        *(bf16x4*)(out + (size_t)bq * CC + h * DH + g * 4) = o;
    }
}

// ---------------------------------------------------------------------------
// Launch
// ---------------------------------------------------------------------------
extern "C" void kernel_launch(void* const* d_in, const int* in_sizes, int n_in,
                              void* d_out, int out_size, void* d_ws, size_t ws_size,
                              hipStream_t stream) {
    const float* query = (const float*)d_in[0];
    const float* refp  = (const float*)d_in[1];
    const float* feat  = (const float*)d_in[2];
    const float* qn_g  = (const float*)d_in[7];
    const float* qn_b  = (const float*)d_in[8];
    const float* fn_g  = (const float*)d_in[9];
    const float* fn_b  = (const float*)d_in[10];
    const float* Wv    = (const float*)d_in[11];
    const float* bv    = (const float*)d_in[12];
    const float* Woff  = (const float*)d_in[13];
    const float* boff  = (const float*)d_in[14];
    const float* Watt  = (const float*)d_in[15];
    const float* batt  = (const float*)d_in[16];
    const float* Wout  = (const float*)d_in[17];
    const float* bout  = (const float*)d_in[18];
    const float* ffn_g = (const float*)d_in[19];
    const float* ffn_b = (const float*)d_in[20];
    const float* W1    = (const float*)d_in[21];
    const float* b1    = (const float*)d_in[22];
    const float* W2    = (const float*)d_in[23];
    const float* b2    = (const float*)d_in[24];
    float* out = (float*)d_out;

    // workspace layout (byte offsets)
    char* ws = (char*)d_ws;
    __bf16* WvT    = (__bf16*)(ws + 0);            // 1179648
    __bf16* WcombT = (__bf16*)(ws + 1179648);      // 192x768x2 = 294912 (slot 393216)
    __bf16* WoutT  = (__bf16*)(ws + 1572864);      // 1179648
    __bf16* W1T    = (__bf16*)(ws + 2752512);      // 192x768x2 = 294912 (slot 393216)
    __bf16* W2T    = (__bf16*)(ws + 3145728);      // 294912
    float*  offatt_f = (float*)(ws + 3670016);     // 9437184
    __bf16* h1_bf    = (__bf16*)offatt_f;          // reuse
    __bf16* bufA     = (__bf16*)(ws + 13107200);   // 25165824
    __bf16* qn_bf    = bufA;
    __bf16* value_bf = bufA;
    __bf16* bufB     = (__bf16*)(ws + 38273024);   // 25165824
    __bf16* fn_bf    = bufB;
    __bf16* samp_bf  = bufB;
    __bf16* h_bf     = bufB;
    __bf16* attn_bf  = (__bf16*)(ws + 63438848);   // 25165824

    dim3 blk(256);

    // 0. batched weight prep (one launch)
    PrepJobs jobs;
    jobs.j[0] = {Wv,   WvT,             768, 768, 768};
    jobs.j[1] = {Woff, WcombT,          768,  96,  96};
    jobs.j[2] = {Watt, WcombT + 96*768, 768,  48,  96};  // comb rows 96..191 (144..191 zero)
    jobs.j[3] = {Wout, WoutT,           768, 768, 768};
    jobs.j[4] = {W1,   W1T,             768, 192, 192};
    jobs.j[5] = {W2,   W2T,             192, 768, 768};
    prep_all<<<dim3(12, 12, 6), blk, 0, stream>>>(jobs);

    // 1. both input LayerNorms in one launch
    ln2_kernel<<<dim3(ROWS, 2), blk, 0, stream>>>(query, qn_g, qn_b, qn_bf,
                                                  feat,  fn_g, fn_b, fn_bf);

    // 2. offatt = qn @ [Woff|Watt] (N=144, Npad=192, f32 out) — 64x64 tiles
    gemm_bt64<<<dim3(3, ROWS / 64), blk, 0, stream>>>(
        qn_bf, WcombT, boff, 96, batt, offatt_f, ROWS, CC, 144, 0);
    // 3. value = fn @ Wv + bv (bf16 out)
    gemm_bt<<<dim3(6, ROWS / 128), blk, 0, stream>>>(
        fn_bf, WvT, bv, CC, nullptr, nullptr, value_bf, ROWS, CC, CC, 2);
    // 4. deformable sampling -> bf16
    sample_kernel<<<ROWS * NH_ / 4, blk, 0, stream>>>(value_bf, offatt_f, refp, samp_bf);
    // 5. attnres = query + samp @ Wout + bout (bf16 out)
    gemm_bt<<<dim3(6, ROWS / 128), blk, 0, stream>>>(
        samp_bf, WoutT, bout, CC, nullptr, query, attn_bf, ROWS, CC, CC, 2);
    // 6. h = LN(attnres) -> bf16
    ln_bf_kernel<<<ROWS, blk, 0, stream>>>(attn_bf, ffn_g, ffn_b, h_bf);
    // 7. h1 = gelu(h @ W1 + b1) -> bf16 (N=192) — 64x64 tiles
    gemm_bt64<<<dim3(3, ROWS / 64), blk, 0, stream>>>(
        h_bf, W1T, b1, HID, nullptr, h1_bf, ROWS, CC, HID, 1 | 2);
    // 8. out = attnres + h1 @ W2 + b2 (K=192, f32 out, bf16 res)
    gemm_bt<<<dim3(6, ROWS / 128), blk, 0, stream>>>(
        h1_bf, W2T, b2, CC, nullptr, attn_bf, out, ROWS, HID, CC, 4);
}

// Round 2
// 438.036 us; speedup vs baseline: 1.0303x; 1.0231x over previous
//
#include <hip/hip_runtime.h>
#include <hip/hip_bf16.h>
#include <math.h>

// Problem constants:
//   B=4, Lq=4096, C=768, NH=12, d=64, NP=4, nl=1, H=W=64, Lin=4096, hid=192
#define B_    4
#define LQ    4096
#define CC    768
#define NH_   12
#define DH    64
#define NP_   4
#define HH    64
#define WW    64
#define HID   192
#define ROWS  (B_ * LQ)          // 16384
#define EPS_  1e-5f

typedef __bf16 bf16x8 __attribute__((ext_vector_type(8)));
typedef __bf16 bf16x4 __attribute__((ext_vector_type(4)));
typedef float  f32x4  __attribute__((ext_vector_type(4)));

typedef __attribute__((address_space(3))) void* lds_vp;
typedef const __attribute__((address_space(1))) void* gbl_vp;

// ---------------------------------------------------------------------------
// Batched weight prep: f32 [K,N] -> bf16 [Npad,K] transposed; rows [N,Npad) zero
// ---------------------------------------------------------------------------
struct PrepJob { const float* W; __bf16* Wt; int K; int N; int Npad; };
struct PrepJobs { PrepJob j[6]; };

__global__ __launch_bounds__(256)
void prep_all(PrepJobs jobs) {
    PrepJob job = jobs.j[blockIdx.z];
    int k0 = blockIdx.x * 64, n0 = blockIdx.y * 64;
    if (k0 >= job.K || n0 >= job.Npad) return;
    __shared__ float tile[64][65];
    int c = threadIdx.x & 63, r0 = threadIdx.x >> 6;
    #pragma unroll
    for (int i = 0; i < 16; ++i) {
        int kk = i * 4 + r0;
        float v = 0.f;
        if (k0 + kk < job.K && n0 + c < job.N) v = job.W[(size_t)(k0 + kk) * job.N + n0 + c];
        tile[kk][c] = v;
    }
    __syncthreads();
    #pragma unroll
    for (int i = 0; i < 16; ++i) {
        int nn = i * 4 + r0;
        if (n0 + nn < job.Npad && k0 + c < job.K)
            job.Wt[(size_t)(n0 + nn) * job.K + k0 + c] = (__bf16)tile[c][nn];
    }
}

// ---------------------------------------------------------------------------
// Reductions
// ---------------------------------------------------------------------------
__inline__ __device__ float wave_sum64(float v) {
    #pragma unroll
    for (int o = 32; o > 0; o >>= 1) v += __shfl_down(v, o, 64);
    return v;
}

// ---------------------------------------------------------------------------
// Fused dual LayerNorm (f32 in, bf16 out), float4 vectorized.
// blockIdx.y selects stream 0 (query) or 1 (feat). 256 thr, 192 active vec4.
// ---------------------------------------------------------------------------
__global__ __launch_bounds__(256)
void ln2_kernel(const float* __restrict__ x0, const float* __restrict__ g0,
                const float* __restrict__ b0, __bf16* __restrict__ y0,
                const float* __restrict__ x1, const float* __restrict__ g1,
                const float* __restrict__ b1, __bf16* __restrict__ y1) {
    int sel = blockIdx.y;
    const float* x = sel ? x1 : x0;
    const float* g = sel ? g1 : g0;
    const float* b = sel ? b1 : b0;
    __bf16* y = sel ? y1 : y0;
    int row = blockIdx.x;
    const float* xr = x + (size_t)row * CC;
    __bf16* yr = y + (size_t)row * CC;
    int t = threadIdx.x;
    f32x4 xv = {0.f, 0.f, 0.f, 0.f};
    if (t < 192) xv = *(const f32x4*)(xr + t * 4);
    float s  = xv[0] + xv[1] + xv[2] + xv[3];
    float s2 = xv[0]*xv[0] + xv[1]*xv[1] + xv[2]*xv[2] + xv[3]*xv[3];
    __shared__ float red[8];
    float ws = wave_sum64(s), ws2 = wave_sum64(s2);
    int w = t >> 6;
    if ((t & 63) == 0) { red[w] = ws; red[4 + w] = ws2; }
    __syncthreads();
    float S  = red[0] + red[1] + red[2] + red[3];
    float S2 = red[4] + red[5] + red[6] + red[7];
    float mean = S / CC;
    float inv  = rsqrtf(S2 / CC - mean * mean + EPS_);
    if (t < 192) {
        f32x4 gv = *(const f32x4*)(g + t * 4);
        f32x4 bv = *(const f32x4*)(b + t * 4);
        bf16x4 o;
        #pragma unroll
        for (int e = 0; e < 4; ++e)
            o[e] = (__bf16)((xv[e] - mean) * inv * gv[e] + bv[e]);
        *(bf16x4*)(yr + t * 4) = o;
    }
}

// ---------------------------------------------------------------------------
// LayerNorm, bf16 in -> bf16 out, bf16x8 vectorized (96 active threads of 256)
// ---------------------------------------------------------------------------
__global__ __launch_bounds__(256)
void ln_bf_kernel(const __bf16* __restrict__ x, const float* __restrict__ g,
                  const float* __restrict__ b, __bf16* __restrict__ y) {
    int row = blockIdx.x;
    const __bf16* xr = x + (size_t)row * CC;
    __bf16* yr = y + (size_t)row * CC;
    int t = threadIdx.x;
    float xv[8]; bf16x8 raw = {};
    if (t < 96) raw = *(const bf16x8*)(xr + t * 8);
    float s = 0.f, s2 = 0.f;
    #pragma unroll
    for (int e = 0; e < 8; ++e) { xv[e] = (float)raw[e]; s += xv[e]; s2 += xv[e]*xv[e]; }
    __shared__ float red[8];
    float ws = wave_sum64(s), ws2 = wave_sum64(s2);
    int w = t >> 6;
    if ((t & 63) == 0) { red[w] = ws; red[4 + w] = ws2; }
    __syncthreads();
    float S  = red[0] + red[1] + red[2] + red[3];
    float S2 = red[4] + red[5] + red[6] + red[7];
    float mean = S / CC;
    float inv  = rsqrtf(S2 / CC - mean * mean + EPS_);
    if (t < 96) {
        bf16x8 o;
        #pragma unroll
        for (int e = 0; e < 8; ++e)
            o[e] = (__bf16)((xv[e] - mean) * inv * g[t * 8 + e] + b[t * 8 + e]);
        *(bf16x8*)(yr + t * 8) = o;
    }
}

// ---------------------------------------------------------------------------
// bf16 MFMA GEMM, 128x128 tile. 3-deep pipeline: 3 LDS buffers, counted
// s_waitcnt vmcnt(N) + raw s_barrier (loads stay in flight across barriers).
// XCD-aware block swizzle (grid always 768 blocks, %8==0 -> bijective).
// flags: 1 gelu, 2 out bf16, 4 res bf16
// ---------------------------------------------------------------------------
__global__ __launch_bounds__(256)
void gemm_bt(const __bf16* __restrict__ A, const __bf16* __restrict__ Bt,
             const float* __restrict__ ba, int Nsplit, const float* __restrict__ bb,
             const void* __restrict__ res, void* __restrict__ out,
             int M, int K, int N, int flags) {
    __shared__ __bf16 As[3][128 * 32];
    __shared__ __bf16 Bs[3][128 * 32];

    int t = threadIdx.x;
    int lane = t & 63, wave = t >> 6;

    // XCD swizzle: consecutive chunks of 1/8th of the grid land on one XCD
    int nwg = gridDim.x * gridDim.y;
    int bid = blockIdx.y * gridDim.x + blockIdx.x;
    int cpx = nwg >> 3;
    int swz = (bid & 7) * cpx + (bid >> 3);
    int bx = swz % gridDim.x, by = swz / gridDim.x;
    int bm = by * 128, bn = bx * 128;

    int wm = wave & 1, wn = wave >> 1;

    f32x4 acc[4][4] = {};

    int row0 = t >> 2,           kc0 = (t & 3) ^ ((row0 >> 1) & 3);
    int row1 = (256 + t) >> 2,   kc1 = ((256 + t) & 3) ^ ((row1 >> 1) & 3);

    const __bf16* a0 = A  + (size_t)(bm + row0) * K + kc0 * 8;
    const __bf16* a1 = A  + (size_t)(bm + row1) * K + kc1 * 8;
    const __bf16* b0 = Bt + (size_t)(bn + row0) * K + kc0 * 8;
    const __bf16* b1 = Bt + (size_t)(bn + row1) * K + kc1 * 8;

    int rbase = wm * 64 + (lane & 15);
    int nbase = wn * 64 + (lane & 15);
    int kq = lane >> 4;

    #define STAGE128(bi, kt) do {                                                              \
        int koff_ = (kt) * 32;                                                                 \
        __builtin_amdgcn_global_load_lds((gbl_vp)(a0 + koff_), (lds_vp)&As[bi][t * 8], 16, 0, 0);         \
        __builtin_amdgcn_global_load_lds((gbl_vp)(a1 + koff_), (lds_vp)&As[bi][(256 + t) * 8], 16, 0, 0); \
        __builtin_amdgcn_global_load_lds((gbl_vp)(b0 + koff_), (lds_vp)&Bs[bi][t * 8], 16, 0, 0);         \
        __builtin_amdgcn_global_load_lds((gbl_vp)(b1 + koff_), (lds_vp)&Bs[bi][(256 + t) * 8], 16, 0, 0); \
    } while (0)

    #define COMPUTE128(bi) do {                                                                \
        bf16x8 afr[4], bfr[4];                                                                 \
        _Pragma("unroll")                                                                      \
        for (int i = 0; i < 4; ++i) {                                                          \
            int r = rbase + i * 16;                                                            \
            afr[i] = *(const bf16x8*)&As[bi][r * 32 + ((kq ^ ((r >> 1) & 3)) * 8)];            \
        }                                                                                      \
        _Pragma("unroll")                                                                      \
        for (int j = 0; j < 4; ++j) {                                                          \
            int n = nbase + j * 16;                                                            \
            bfr[j] = *(const bf16x8*)&Bs[bi][n * 32 + ((kq ^ ((n >> 1) & 3)) * 8)];            \
        }                                                                                      \
        _Pragma("unroll")                                                                      \
        for (int i = 0; i < 4; ++i)                                                            \
            _Pragma("unroll")                                                                  \
            for (int j = 0; j < 4; ++j)                                                        \
                acc[i][j] = __builtin_amdgcn_mfma_f32_16x16x32_bf16(afr[i], bfr[j], acc[i][j], 0, 0, 0); \
    } while (0)

    int nt = K >> 5;   // K/32, always >= 6 here
    // prologue: stage tiles 0 and 1 (8 loads in flight)
    STAGE128(0, 0);
    STAGE128(1, 1);
    int bi = 0;
    for (int tt = 0; tt < nt - 2; ++tt) {
        int bnxt = bi + 2; if (bnxt >= 3) bnxt -= 3;
        STAGE128(bnxt, tt + 2);                       // 12 in flight
        // wait for tile tt's 4 loads only; 8 newer stay in flight across barrier
        asm volatile("s_waitcnt vmcnt(8)\n\ts_barrier" ::: "memory");
        COMPUTE128(bi);
        asm volatile("s_barrier" ::: "memory");       // all waves done reading buf bi
        ++bi; if (bi >= 3) bi -= 3;
    }
    // tail: tiles nt-2, nt-1 (8 then 4 loads in flight)
    asm volatile("s_waitcnt vmcnt(4)\n\ts_barrier" ::: "memory");
    COMPUTE128(bi);
    asm volatile("s_barrier" ::: "memory");
    ++bi; if (bi >= 3) bi -= 3;
    asm volatile("s_waitcnt vmcnt(0)\n\ts_barrier" ::: "memory");
    COMPUTE128(bi);

    #undef STAGE128
    #undef COMPUTE128

    int rowq = lane >> 4;
    int colj[4]; float biasj[4];
    #pragma unroll
    for (int j = 0; j < 4; ++j) {
        int c = bn + wn * 64 + j * 16 + (lane & 15);
        colj[j] = c;
        biasj[j] = (c < N) ? ((c < Nsplit) ? ba[c] : bb[c - Nsplit]) : 0.f;
    }
    int do_gelu = flags & 1, out_bf = flags & 2, res_bf = flags & 4;
    #pragma unroll
    for (int i = 0; i < 4; ++i) {
        #pragma unroll
        for (int r = 0; r < 4; ++r) {
            int m = bm + wm * 64 + i * 16 + rowq * 4 + r;
            #pragma unroll
            for (int j = 0; j < 4; ++j) {
                if (colj[j] < N) {
                    float v = acc[i][j][r] + biasj[j];
                    if (do_gelu) v = 0.5f * v * (1.f + erff(v * 0.70710678118f));
                    size_t oi = (size_t)m * N + colj[j];
                    if (res) v += res_bf ? (float)((const __bf16*)res)[oi]
                                         : ((const float*)res)[oi];
                    if (out_bf) ((__bf16*)out)[oi] = (__bf16)v;
                    else        ((float*)out)[oi]  = v;
                }
            }
        }
    }
}

// ---------------------------------------------------------------------------
// 64x64-tile GEMM for small N (144/192), same 3-deep counted-vmcnt pipeline.
// Grid: (Npad/64, M/64) = 768 blocks. flags: 1 gelu, 2 out bf16
// ---------------------------------------------------------------------------
__global__ __launch_bounds__(256)
void gemm_bt64(const __bf16* __restrict__ A, const __bf16* __restrict__ Bt,
               const float* __restrict__ ba, int Nsplit, const float* __restrict__ bb,
               void* __restrict__ out, int M, int K, int N, int flags) {
    __shared__ __bf16 As[3][64 * 32];
    __shared__ __bf16 Bs[3][64 * 32];

    int t = threadIdx.x;
    int lane = t & 63, wave = t >> 6;

    int nwg = gridDim.x * gridDim.y;
    int bid = blockIdx.y * gridDim.x + blockIdx.x;
    int cpx = nwg >> 3;
    int swz = (bid & 7) * cpx + (bid >> 3);
    int bx = swz % gridDim.x, by = swz / gridDim.x;
    int bm = by * 64, bn = bx * 64;

    f32x4 acc[4] = {};

    int row0 = t >> 2, kc0 = (t & 3) ^ ((row0 >> 1) & 3);
    const __bf16* a0 = A  + (size_t)(bm + row0) * K + kc0 * 8;
    const __bf16* b0 = Bt + (size_t)(bn + row0) * K + kc0 * 8;

    int rbase = wave * 16 + (lane & 15);
    int nbase = lane & 15;
    int kq = lane >> 4;

    #define STAGE64(bi, kt) do {                                                               \
        int koff_ = (kt) * 32;                                                                 \
        __builtin_amdgcn_global_load_lds((gbl_vp)(a0 + koff_), (lds_vp)&As[bi][t * 8], 16, 0, 0); \
        __builtin_amdgcn_global_load_lds((gbl_vp)(b0 + koff_), (lds_vp)&Bs[bi][t * 8], 16, 0, 0); \
    } while (0)

    #define COMPUTE64(bi) do {                                                                 \
        bf16x8 afr = *(const bf16x8*)&As[bi][rbase * 32 + ((kq ^ ((rbase >> 1) & 3)) * 8)];    \
        _Pragma("unroll")                                                                      \
        for (int j = 0; j < 4; ++j) {                                                          \
            int n = nbase + j * 16;                                                            \
            bf16x8 bfr = *(const bf16x8*)&Bs[bi][n * 32 + ((kq ^ ((n >> 1) & 3)) * 8)];        \
            acc[j] = __builtin_amdgcn_mfma_f32_16x16x32_bf16(afr, bfr, acc[j], 0, 0, 0);       \
        }                                                                                      \
    } while (0)

    int nt = K >> 5;
    STAGE64(0, 0);
    STAGE64(1, 1);
    int bi = 0;
    for (int tt = 0; tt < nt - 2; ++tt) {
        int bnxt = bi + 2; if (bnxt >= 3) bnxt -= 3;
        STAGE64(bnxt, tt + 2);                        // 6 in flight
        asm volatile("s_waitcnt vmcnt(4)\n\ts_barrier" ::: "memory");
        COMPUTE64(bi);
        asm volatile("s_barrier" ::: "memory");
        ++bi; if (bi >= 3) bi -= 3;
    }
    asm volatile("s_waitcnt vmcnt(2)\n\ts_barrier" ::: "memory");
    COMPUTE64(bi);
    asm volatile("s_barrier" ::: "memory");
    ++bi; if (bi >= 3) bi -= 3;
    asm volatile("s_waitcnt vmcnt(0)\n\ts_barrier" ::: "memory");
    COMPUTE64(bi);

    #undef STAGE64
    #undef COMPUTE64

    int rowq = lane >> 4;
    int do_gelu = flags & 1, out_bf = flags & 2;
    #pragma unroll
    for (int r = 0; r < 4; ++r) {
        int m = bm + wave * 16 + rowq * 4 + r;
        #pragma unroll
        for (int j = 0; j < 4; ++j) {
            int c = bn + j * 16 + (lane & 15);
            if (c < N) {
                float v = acc[j][r] + ((c < Nsplit) ? ba[c] : bb[c - Nsplit]);
                if (do_gelu) v = 0.5f * v * (1.f + erff(v * 0.70710678118f));
                size_t oi = (size_t)m * N + c;
                if (out_bf) ((__bf16*)out)[oi] = (__bf16)v;
                else        ((float*)out)[oi]  = v;
            }
        }
    }
}

// ---------------------------------------------------------------------------
// Deformable sampling v3: one wave per (b,q,h).
//   lane = p*16 + g : p = sample point (0..3), g = channel group (4 bf16).
// Each lane: one coord chain, 4 in-lane corner loads (constant cx/cy).
// Butterfly (xor 16,32) sums points; lanes p==0 store bf16x4.
// ---------------------------------------------------------------------------
__global__ __launch_bounds__(256)
void sample_kernel(const __bf16* __restrict__ value, const float* __restrict__ offatt,
                   const float* __restrict__ refp, __bf16* __restrict__ out) {
    int wid  = blockIdx.x * 4 + (threadIdx.x >> 6);
    int lane = threadIdx.x & 63;
    int h  = wid % NH_;
    int bq = wid / NH_;
    int b  = bq / LQ;

    const float* oa = offatt + (size_t)bq * 144;
    float rx = refp[(size_t)bq * 2 + 0] * (float)WW - 0.5f;
    float ry = refp[(size_t)bq * 2 + 1] * (float)HH - 0.5f;

    // softmax over this head's 4 logits (wave-uniform -> s_loads)
    float l0 = oa[96 + h * 4 + 0], l1 = oa[96 + h * 4 + 1];
    float l2 = oa[96 + h * 4 + 2], l3 = oa[96 + h * 4 + 3];
    float mx = fmaxf(fmaxf(l0, l1), fmaxf(l2, l3));
    float e0 = __expf(l0 - mx), e1 = __expf(l1 - mx);
    float e2 = __expf(l2 - mx), e3 = __expf(l3 - mx);
    float rs = 1.f / (e0 + e1 + e2 + e3);

    int pp = lane >> 4;       // point id
    int g  = lane & 15;       // channel group
    float wpl = (pp == 0) ? e0 : (pp == 1) ? e1 : (pp == 2) ? e2 : e3;
    wpl *= rs;

    // per-lane point coords (8B vector load, divergent by pp)
    const float* oxy = oa + h * 8 + pp * 2;
    float x = rx + oxy[0];
    float y = ry + oxy[1];
    float x0f = floorf(x), y0f = floorf(y);
    float wx1 = x - x0f, wy1 = y - y0f;
    float wx0 = 1.f - wx1, wy0 = 1.f - wy1;
    int x0 = (int)x0f, y0 = (int)y0f;
    int x1 = x0 + 1, y1 = y0 + 1;
    // zero weights at OOB; address clamp via &63 (weight already 0 there)
    float mx0 = ((unsigned)x0 < (unsigned)WW) ? wx0 : 0.f;
    float mx1 = ((unsigned)x1 < (unsigned)WW) ? wx1 : 0.f;
    float my0 = (((unsigned)y0 < (unsigned)HH) ? wy0 : 0.f) * wpl;
    float my1 = (((unsigned)y1 < (unsigned)HH) ? wy1 : 0.f) * wpl;
    int xc0 = x0 & (WW - 1), xc1 = x1 & (WW - 1);
    int r0 = (y0 & (HH - 1)) << 6, r1 = (y1 & (HH - 1)) << 6;

    const __bf16* vbase = value + (size_t)b * (LQ * CC) + h * DH + g * 4;
    bf16x4 v00 = *(const bf16x4*)(vbase + (size_t)(r0 + xc0) * CC);
    bf16x4 v01 = *(const bf16x4*)(vbase + (size_t)(r0 + xc1) * CC);
    bf16x4 v10 = *(const bf16x4*)(vbase + (size_t)(r1 + xc0) * CC);
    bf16x4 v11 = *(const bf16x4*)(vbase + (size_t)(r1 + xc1) * CC);
    float w00 = mx0 * my0, w01 = mx1 * my0, w10 = mx0 * my1, w11 = mx1 * my1;

    f32x4 acc;
    #pragma unroll
    for (int e = 0; e < 4; ++e)
        acc[e] = w00 * (float)v00[e] + w01 * (float)v01[e]
               + w10 * (float)v10[e] + w11 * (float)v11[e];

    #pragma unroll
    for (int e = 0; e < 4; ++e) {
        acc[e] += __shfl_xor(acc[e], 16, 64);
        acc[e] += __shfl_xor(acc[e], 32, 64);
    }
    if (pp == 0) {
        bf16x4 o;
        o[0] = (__bf16)acc[0]; o[1] = (__bf16)acc[1];
        o[2] = (__bf16)acc[2]; o[3] = (__bf16)acc[3];
        *(bf16x4*)(out + (size_t)bq * CC + h * DH + g * 4) = o;
    }
}

// ---------------------------------------------------------------------------
// Launch
// ---------------------------------------------------------------------------
extern "C" void kernel_launch(void* const* d_in, const int* in_sizes, int n_in,
                              void* d_out, int out_size, void* d_ws, size_t ws_size,
                              hipStream_t stream) {
    const float* query = (const float*)d_in[0];
    const float* refp  = (const float*)d_in[1];
    const float* feat  = (const float*)d_in[2];
    const float* qn_g  = (const float*)d_in[7];
    const float* qn_b  = (const float*)d_in[8];
    const float* fn_g  = (const float*)d_in[9];
    const float* fn_b  = (const float*)d_in[10];
    const float* Wv    = (const float*)d_in[11];
    const float* bv    = (const float*)d_in[12];
    const float* Woff  = (const float*)d_in[13];
    const float* boff  = (const float*)d_in[14];
    const float* Watt  = (const float*)d_in[15];
    const float* batt  = (const float*)d_in[16];
    const float* Wout  = (const float*)d_in[17];
    const float* bout  = (const float*)d_in[18];
    const float* ffn_g = (const float*)d_in[19];
    const float* ffn_b = (const float*)d_in[20];
    const float* W1    = (const float*)d_in[21];
    const float* b1    = (const float*)d_in[22];
    const float* W2    = (const float*)d_in[23];
    const float* b2    = (const float*)d_in[24];
    float* out = (float*)d_out;

    // workspace layout (byte offsets)
    char* ws = (char*)d_ws;
    __bf16* WvT    = (__bf16*)(ws + 0);            // 1179648
    __bf16* WcombT = (__bf16*)(ws + 1179648);      // 192x768x2 = 294912 (slot 393216)
    __bf16* WoutT  = (__bf16*)(ws + 1572864);      // 1179648
    __bf16* W1T    = (__bf16*)(ws + 2752512);      // 192x768x2 = 294912 (slot 393216)
    __bf16* W2T    = (__bf16*)(ws + 3145728);      // 294912
    float*  offatt_f = (float*)(ws + 3670016);     // 9437184
    __bf16* h1_bf    = (__bf16*)offatt_f;          // reuse
    __bf16* bufA     = (__bf16*)(ws + 13107200);   // 25165824
    __bf16* qn_bf    = bufA;
    __bf16* value_bf = bufA;
    __bf16* bufB     = (__bf16*)(ws + 38273024);   // 25165824
    __bf16* fn_bf    = bufB;
    __bf16* samp_bf  = bufB;
    __bf16* h_bf     = bufB;
    __bf16* attn_bf  = (__bf16*)(ws + 63438848);   // 25165824

    dim3 blk(256);

    // 0. batched weight prep (one launch)
    PrepJobs jobs;
    jobs.j[0] = {Wv,   WvT,             768, 768, 768};
    jobs.j[1] = {Woff, WcombT,          768,  96,  96};
    jobs.j[2] = {Watt, WcombT + 96*768, 768,  48,  96};  // comb rows 96..191 (144..191 zero)
    jobs.j[3] = {Wout, WoutT,           768, 768, 768};
    jobs.j[4] = {W1,   W1T,             768, 192, 192};
    jobs.j[5] = {W2,   W2T,             192, 768, 768};
    prep_all<<<dim3(12, 12, 6), blk, 0, stream>>>(jobs);

    // 1. both input LayerNorms in one launch
    ln2_kernel<<<dim3(ROWS, 2), blk, 0, stream>>>(query, qn_g, qn_b, qn_bf,
                                                  feat,  fn_g, fn_b, fn_bf);

    // 2. offatt = qn @ [Woff|Watt] (N=144, Npad=192, f32 out) — 64x64 tiles
    gemm_bt64<<<dim3(3, ROWS / 64), blk, 0, stream>>>(
        qn_bf, WcombT, boff, 96, batt, offatt_f, ROWS, CC, 144, 0);
    // 3. value = fn @ Wv + bv (bf16 out)
    gemm_bt<<<dim3(6, ROWS / 128), blk, 0, stream>>>(
        fn_bf, WvT, bv, CC, nullptr, nullptr, value_bf, ROWS, CC, CC, 2);
    // 4. deformable sampling -> bf16
    sample_kernel<<<ROWS * NH_ / 4, blk, 0, stream>>>(value_bf, offatt_f, refp, samp_bf);
    // 5. attnres = query + samp @ Wout + bout (bf16 out)
    gemm_bt<<<dim3(6, ROWS / 128), blk, 0, stream>>>(
        samp_bf, WoutT, bout, CC, nullptr, query, attn_bf, ROWS, CC, CC, 2);
    // 6. h = LN(attnres) -> bf16
    ln_bf_kernel<<<ROWS, blk, 0, stream>>>(attn_bf, ffn_g, ffn_b, h_bf);
    // 7. h1 = gelu(h @ W1 + b1) -> bf16 (N=192) — 64x64 tiles
    gemm_bt64<<<dim3(3, ROWS / 64), blk, 0, stream>>>(
        h_bf, W1T, b1, HID, nullptr, h1_bf, ROWS, CC, HID, 1 | 2);
    // 8. out = attnres + h1 @ W2 + b2 (K=192, f32 out, bf16 res)
    gemm_bt<<<dim3(6, ROWS / 128), blk, 0, stream>>>(
        h1_bf, W2T, b2, CC, nullptr, attn_bf, out, ROWS, HID, CC, 4);
}

// Round 3
// 431.410 us; speedup vs baseline: 1.0461x; 1.0154x over previous
//
#include <hip/hip_runtime.h>
#include <hip/hip_bf16.h>
#include <math.h>

// Problem constants:
//   B=4, Lq=4096, C=768, NH=12, d=64, NP=4, nl=1, H=W=64, Lin=4096, hid=192
#define B_    4
#define LQ    4096
#define CC    768
#define NH_   12
#define DH    64
#define NP_   4
#define HH    64
#define WW    64
#define HID   192
#define ROWS  (B_ * LQ)          // 16384
#define EPS_  1e-5f

typedef __bf16 bf16x8 __attribute__((ext_vector_type(8)));
typedef __bf16 bf16x4 __attribute__((ext_vector_type(4)));
typedef float  f32x4  __attribute__((ext_vector_type(4)));

typedef __attribute__((address_space(3))) void* lds_vp;
typedef const __attribute__((address_space(1))) void* gbl_vp;

// ---------------------------------------------------------------------------
// Batched weight prep: f32 [K,N] -> bf16 [Npad,K] transposed; rows [N,Npad) zero
// ---------------------------------------------------------------------------
struct PrepJob { const float* W; __bf16* Wt; int K; int N; int Npad; };
struct PrepJobs { PrepJob j[6]; };

__global__ __launch_bounds__(256)
void prep_all(PrepJobs jobs) {
    PrepJob job = jobs.j[blockIdx.z];
    int k0 = blockIdx.x * 64, n0 = blockIdx.y * 64;
    if (k0 >= job.K || n0 >= job.Npad) return;
    __shared__ float tile[64][65];
    int c = threadIdx.x & 63, r0 = threadIdx.x >> 6;
    #pragma unroll
    for (int i = 0; i < 16; ++i) {
        int kk = i * 4 + r0;
        float v = 0.f;
        if (k0 + kk < job.K && n0 + c < job.N) v = job.W[(size_t)(k0 + kk) * job.N + n0 + c];
        tile[kk][c] = v;
    }
    __syncthreads();
    #pragma unroll
    for (int i = 0; i < 16; ++i) {
        int nn = i * 4 + r0;
        if (n0 + nn < job.Npad && k0 + c < job.K)
            job.Wt[(size_t)(n0 + nn) * job.K + k0 + c] = (__bf16)tile[c][nn];
    }
}

// ---------------------------------------------------------------------------
// Reductions
// ---------------------------------------------------------------------------
__inline__ __device__ float wave_sum64(float v) {
    #pragma unroll
    for (int o = 32; o > 0; o >>= 1) v += __shfl_down(v, o, 64);
    return v;
}

// ---------------------------------------------------------------------------
// Fused dual LayerNorm (f32 in, bf16 out), float4 vectorized.
// blockIdx.y selects stream 0 (query) or 1 (feat). 256 thr, 192 active vec4.
// ---------------------------------------------------------------------------
__global__ __launch_bounds__(256)
void ln2_kernel(const float* __restrict__ x0, const float* __restrict__ g0,
                const float* __restrict__ b0, __bf16* __restrict__ y0,
                const float* __restrict__ x1, const float* __restrict__ g1,
                const float* __restrict__ b1, __bf16* __restrict__ y1) {
    int sel = blockIdx.y;
    const float* x = sel ? x1 : x0;
    const float* g = sel ? g1 : g0;
    const float* b = sel ? b1 : b0;
    __bf16* y = sel ? y1 : y0;
    int row = blockIdx.x;
    const float* xr = x + (size_t)row * CC;
    __bf16* yr = y + (size_t)row * CC;
    int t = threadIdx.x;
    f32x4 xv = {0.f, 0.f, 0.f, 0.f};
    if (t < 192) xv = *(const f32x4*)(xr + t * 4);
    float s  = xv[0] + xv[1] + xv[2] + xv[3];
    float s2 = xv[0]*xv[0] + xv[1]*xv[1] + xv[2]*xv[2] + xv[3]*xv[3];
    __shared__ float red[8];
    float ws = wave_sum64(s), ws2 = wave_sum64(s2);
    int w = t >> 6;
    if ((t & 63) == 0) { red[w] = ws; red[4 + w] = ws2; }
    __syncthreads();
    float S  = red[0] + red[1] + red[2] + red[3];
    float S2 = red[4] + red[5] + red[6] + red[7];
    float mean = S / CC;
    float inv  = rsqrtf(S2 / CC - mean * mean + EPS_);
    if (t < 192) {
        f32x4 gv = *(const f32x4*)(g + t * 4);
        f32x4 bv = *(const f32x4*)(b + t * 4);
        bf16x4 o;
        #pragma unroll
        for (int e = 0; e < 4; ++e)
            o[e] = (__bf16)((xv[e] - mean) * inv * gv[e] + bv[e]);
        *(bf16x4*)(yr + t * 4) = o;
    }
}

// ---------------------------------------------------------------------------
// LayerNorm, bf16 in -> bf16 out, bf16x8 vectorized (96 active threads of 256)
// ---------------------------------------------------------------------------
__global__ __launch_bounds__(256)
void ln_bf_kernel(const __bf16* __restrict__ x, const float* __restrict__ g,
                  const float* __restrict__ b, __bf16* __restrict__ y) {
    int row = blockIdx.x;
    const __bf16* xr = x + (size_t)row * CC;
    __bf16* yr = y + (size_t)row * CC;
    int t = threadIdx.x;
    float xv[8]; bf16x8 raw = {};
    if (t < 96) raw = *(const bf16x8*)(xr + t * 8);
    float s = 0.f, s2 = 0.f;
    #pragma unroll
    for (int e = 0; e < 8; ++e) { xv[e] = (float)raw[e]; s += xv[e]; s2 += xv[e]*xv[e]; }
    __shared__ float red[8];
    float ws = wave_sum64(s), ws2 = wave_sum64(s2);
    int w = t >> 6;
    if ((t & 63) == 0) { red[w] = ws; red[4 + w] = ws2; }
    __syncthreads();
    float S  = red[0] + red[1] + red[2] + red[3];
    float S2 = red[4] + red[5] + red[6] + red[7];
    float mean = S / CC;
    float inv  = rsqrtf(S2 / CC - mean * mean + EPS_);
    if (t < 96) {
        bf16x8 o;
        #pragma unroll
        for (int e = 0; e < 8; ++e)
            o[e] = (__bf16)((xv[e] - mean) * inv * g[t * 8 + e] + b[t * 8 + e]);
        *(bf16x8*)(yr + t * 8) = o;
    }
}

// ---------------------------------------------------------------------------
// Unified 64x64-tile bf16 MFMA GEMM. 2-buffer LDS (16 KB), counted vmcnt,
// raw s_barrier, XCD-aware swizzle (grids always %8==0 -> bijective).
// 8 blocks/CU (32 waves/CU) for maximum latency hiding via TLP.
// Wave w owns rows [w*16, w*16+16) of the 64x64 tile: acc[4] (16x16 each).
// flags: 1 gelu, 2 out bf16, 4 res bf16
// ---------------------------------------------------------------------------
__global__ __launch_bounds__(256, 8)
void gemm64(const __bf16* __restrict__ A, const __bf16* __restrict__ Bt,
            const float* __restrict__ ba, int Nsplit, const float* __restrict__ bb,
            const void* __restrict__ res, void* __restrict__ out,
            int M, int K, int N, int flags) {
    __shared__ __bf16 As[2][64 * 32];
    __shared__ __bf16 Bs[2][64 * 32];

    int t = threadIdx.x;
    int lane = t & 63, wave = t >> 6;

    // XCD swizzle: contiguous chunk of 1/8th of the grid per XCD
    int nwg = gridDim.x * gridDim.y;
    int bid = blockIdx.y * gridDim.x + blockIdx.x;
    int swz = (bid & 7) * (nwg >> 3) + (bid >> 3);
    int bx = swz % gridDim.x, by = swz / gridDim.x;
    int bm = by * 64, bn = bx * 64;

    f32x4 acc[4] = {};

    int row0 = t >> 2, kc0 = (t & 3) ^ ((row0 >> 1) & 3);
    const __bf16* a0 = A  + (size_t)(bm + row0) * K + kc0 * 8;
    const __bf16* b0 = Bt + (size_t)(bn + row0) * K + kc0 * 8;

    int rbase = wave * 16 + (lane & 15);
    int nbase = lane & 15;
    int kq = lane >> 4;

    #define STAGE(bi, kt) do {                                                                   \
        int koff_ = (kt) * 32;                                                                   \
        __builtin_amdgcn_global_load_lds((gbl_vp)(a0 + koff_), (lds_vp)&As[bi][t * 8], 16, 0, 0); \
        __builtin_amdgcn_global_load_lds((gbl_vp)(b0 + koff_), (lds_vp)&Bs[bi][t * 8], 16, 0, 0); \
    } while (0)

    #define COMPUTE(bi) do {                                                                     \
        bf16x8 afr = *(const bf16x8*)&As[bi][rbase * 32 + ((kq ^ ((rbase >> 1) & 3)) * 8)];      \
        _Pragma("unroll")                                                                        \
        for (int j = 0; j < 4; ++j) {                                                            \
            int n = nbase + j * 16;                                                              \
            bf16x8 bfr = *(const bf16x8*)&Bs[bi][n * 32 + ((kq ^ ((n >> 1) & 3)) * 8)];          \
            acc[j] = __builtin_amdgcn_mfma_f32_16x16x32_bf16(afr, bfr, acc[j], 0, 0, 0);         \
        }                                                                                        \
    } while (0)

    int nt = K >> 5;   // K/32: 24 (K=768) or 6 (K=192)
    // prologue: tiles 0 and 1 in flight (4 loads)
    STAGE(0, 0);
    STAGE(1, 1);
    for (int tt = 0; tt < nt; ++tt) {
        int cur = tt & 1;
        // wait for tile tt's 2 loads; tile tt+1's 2 stay in flight across barrier
        if (tt < nt - 1) asm volatile("s_waitcnt vmcnt(2)\n\ts_barrier" ::: "memory");
        else             asm volatile("s_waitcnt vmcnt(0)\n\ts_barrier" ::: "memory");
        COMPUTE(cur);
        // all waves done reading buf cur before restaging it
        asm volatile("s_waitcnt lgkmcnt(0)\n\ts_barrier" ::: "memory");
        if (tt + 2 < nt) STAGE(cur, tt + 2);
    }

    #undef STAGE
    #undef COMPUTE

    int rowq = lane >> 4;
    int do_gelu = flags & 1, out_bf = flags & 2, res_bf = flags & 4;
    #pragma unroll
    for (int j = 0; j < 4; ++j) {
        int c = bn + j * 16 + (lane & 15);
        if (c < N) {
            float bias = (c < Nsplit) ? ba[c] : bb[c - Nsplit];
            #pragma unroll
            for (int r = 0; r < 4; ++r) {
                int m = bm + wave * 16 + rowq * 4 + r;
                float v = acc[j][r] + bias;
                if (do_gelu) v = 0.5f * v * (1.f + erff(v * 0.70710678118f));
                size_t oi = (size_t)m * N + c;
                if (res) v += res_bf ? (float)((const __bf16*)res)[oi]
                                     : ((const float*)res)[oi];
                if (out_bf) ((__bf16*)out)[oi] = (__bf16)v;
                else        ((float*)out)[oi]  = v;
            }
        }
    }
}

// ---------------------------------------------------------------------------
// Deformable sampling v3: one wave per (b,q,h).
//   lane = p*16 + g : p = sample point (0..3), g = channel group (4 bf16).
// Each lane: one coord chain, 4 in-lane corner loads (constant cx/cy).
// Butterfly (xor 16,32) sums points; lanes p==0 store bf16x4.
// ---------------------------------------------------------------------------
__global__ __launch_bounds__(256)
void sample_kernel(const __bf16* __restrict__ value, const float* __restrict__ offatt,
                   const float* __restrict__ refp, __bf16* __restrict__ out) {
    int wid  = blockIdx.x * 4 + (threadIdx.x >> 6);
    int lane = threadIdx.x & 63;
    int h  = wid % NH_;
    int bq = wid / NH_;
    int b  = bq / LQ;

    const float* oa = offatt + (size_t)bq * 144;
    float rx = refp[(size_t)bq * 2 + 0] * (float)WW - 0.5f;
    float ry = refp[(size_t)bq * 2 + 1] * (float)HH - 0.5f;

    // softmax over this head's 4 logits (wave-uniform -> s_loads)
    float l0 = oa[96 + h * 4 + 0], l1 = oa[96 + h * 4 + 1];
    float l2 = oa[96 + h * 4 + 2], l3 = oa[96 + h * 4 + 3];
    float mx = fmaxf(fmaxf(l0, l1), fmaxf(l2, l3));
    float e0 = __expf(l0 - mx), e1 = __expf(l1 - mx);
    float e2 = __expf(l2 - mx), e3 = __expf(l3 - mx);
    float rs = 1.f / (e0 + e1 + e2 + e3);

    int pp = lane >> 4;       // point id
    int g  = lane & 15;       // channel group
    float wpl = (pp == 0) ? e0 : (pp == 1) ? e1 : (pp == 2) ? e2 : e3;
    wpl *= rs;

    // per-lane point coords (8B vector load, divergent by pp)
    const float* oxy = oa + h * 8 + pp * 2;
    float x = rx + oxy[0];
    float y = ry + oxy[1];
    float x0f = floorf(x), y0f = floorf(y);
    float wx1 = x - x0f, wy1 = y - y0f;
    float wx0 = 1.f - wx1, wy0 = 1.f - wy1;
    int x0 = (int)x0f, y0 = (int)y0f;
    int x1 = x0 + 1, y1 = y0 + 1;
    // zero weights at OOB; address clamp via &63 (weight already 0 there)
    float mx0 = ((unsigned)x0 < (unsigned)WW) ? wx0 : 0.f;
    float mx1 = ((unsigned)x1 < (unsigned)WW) ? wx1 : 0.f;
    float my0 = (((unsigned)y0 < (unsigned)HH) ? wy0 : 0.f) * wpl;
    float my1 = (((unsigned)y1 < (unsigned)HH) ? wy1 : 0.f) * wpl;
    int xc0 = x0 & (WW - 1), xc1 = x1 & (WW - 1);
    int r0 = (y0 & (HH - 1)) << 6, r1 = (y1 & (HH - 1)) << 6;

    const __bf16* vbase = value + (size_t)b * (LQ * CC) + h * DH + g * 4;
    bf16x4 v00 = *(const bf16x4*)(vbase + (size_t)(r0 + xc0) * CC);
    bf16x4 v01 = *(const bf16x4*)(vbase + (size_t)(r0 + xc1) * CC);
    bf16x4 v10 = *(const bf16x4*)(vbase + (size_t)(r1 + xc0) * CC);
    bf16x4 v11 = *(const bf16x4*)(vbase + (size_t)(r1 + xc1) * CC);
    float w00 = mx0 * my0, w01 = mx1 * my0, w10 = mx0 * my1, w11 = mx1 * my1;

    f32x4 acc;
    #pragma unroll
    for (int e = 0; e < 4; ++e)
        acc[e] = w00 * (float)v00[e] + w01 * (float)v01[e]
               + w10 * (float)v10[e] + w11 * (float)v11[e];

    #pragma unroll
    for (int e = 0; e < 4; ++e) {
        acc[e] += __shfl_xor(acc[e], 16, 64);
        acc[e] += __shfl_xor(acc[e], 32, 64);
    }
    if (pp == 0) {
        bf16x4 o;
        o[0] = (__bf16)acc[0]; o[1] = (__bf16)acc[1];
        o[2] = (__bf16)acc[2]; o[3] = (__bf16)acc[3];
        *(bf16x4*)(out + (size_t)bq * CC + h * DH + g * 4) = o;
    }
}

// ---------------------------------------------------------------------------
// Launch
// ---------------------------------------------------------------------------
extern "C" void kernel_launch(void* const* d_in, const int* in_sizes, int n_in,
                              void* d_out, int out_size, void* d_ws, size_t ws_size,
                              hipStream_t stream) {
    const float* query = (const float*)d_in[0];
    const float* refp  = (const float*)d_in[1];
    const float* feat  = (const float*)d_in[2];
    const float* qn_g  = (const float*)d_in[7];
    const float* qn_b  = (const float*)d_in[8];
    const float* fn_g  = (const float*)d_in[9];
    const float* fn_b  = (const float*)d_in[10];
    const float* Wv    = (const float*)d_in[11];
    const float* bv    = (const float*)d_in[12];
    const float* Woff  = (const float*)d_in[13];
    const float* boff  = (const float*)d_in[14];
    const float* Watt  = (const float*)d_in[15];
    const float* batt  = (const float*)d_in[16];
    const float* Wout  = (const float*)d_in[17];
    const float* bout  = (const float*)d_in[18];
    const float* ffn_g = (const float*)d_in[19];
    const float* ffn_b = (const float*)d_in[20];
    const float* W1    = (const float*)d_in[21];
    const float* b1    = (const float*)d_in[22];
    const float* W2    = (const float*)d_in[23];
    const float* b2    = (const float*)d_in[24];
    float* out = (float*)d_out;

    // workspace layout (byte offsets)
    char* ws = (char*)d_ws;
    __bf16* WvT    = (__bf16*)(ws + 0);            // 1179648
    __bf16* WcombT = (__bf16*)(ws + 1179648);      // 192x768x2 = 294912 (slot 393216)
    __bf16* WoutT  = (__bf16*)(ws + 1572864);      // 1179648
    __bf16* W1T    = (__bf16*)(ws + 2752512);      // 192x768x2 = 294912 (slot 393216)
    __bf16* W2T    = (__bf16*)(ws + 3145728);      // 294912
    float*  offatt_f = (float*)(ws + 3670016);     // 9437184
    __bf16* h1_bf    = (__bf16*)offatt_f;          // reuse
    __bf16* bufA     = (__bf16*)(ws + 13107200);   // 25165824
    __bf16* qn_bf    = bufA;
    __bf16* value_bf = bufA;
    __bf16* bufB     = (__bf16*)(ws + 38273024);   // 25165824
    __bf16* fn_bf    = bufB;
    __bf16* samp_bf  = bufB;
    __bf16* h_bf     = bufB;
    __bf16* attn_bf  = (__bf16*)(ws + 63438848);   // 25165824

    dim3 blk(256);

    // 0. batched weight prep (one launch)
    PrepJobs jobs;
    jobs.j[0] = {Wv,   WvT,             768, 768, 768};
    jobs.j[1] = {Woff, WcombT,          768,  96,  96};
    jobs.j[2] = {Watt, WcombT + 96*768, 768,  48,  96};  // comb rows 96..191 (144..191 zero)
    jobs.j[3] = {Wout, WoutT,           768, 768, 768};
    jobs.j[4] = {W1,   W1T,             768, 192, 192};
    jobs.j[5] = {W2,   W2T,             192, 768, 768};
    prep_all<<<dim3(12, 12, 6), blk, 0, stream>>>(jobs);

    // 1. both input LayerNorms in one launch
    ln2_kernel<<<dim3(ROWS, 2), blk, 0, stream>>>(query, qn_g, qn_b, qn_bf,
                                                  feat,  fn_g, fn_b, fn_bf);

    // 2. offatt = qn @ [Woff|Watt] (N=144, Npad=192, f32 out)
    gemm64<<<dim3(3, ROWS / 64), blk, 0, stream>>>(
        qn_bf, WcombT, boff, 96, batt, nullptr, offatt_f, ROWS, CC, 144, 0);
    // 3. value = fn @ Wv + bv (bf16 out)
    gemm64<<<dim3(12, ROWS / 64), blk, 0, stream>>>(
        fn_bf, WvT, bv, CC, nullptr, nullptr, value_bf, ROWS, CC, CC, 2);
    // 4. deformable sampling -> bf16
    sample_kernel<<<ROWS * NH_ / 4, blk, 0, stream>>>(value_bf, offatt_f, refp, samp_bf);
    // 5. attnres = query + samp @ Wout + bout (bf16 out)
    gemm64<<<dim3(12, ROWS / 64), blk, 0, stream>>>(
        samp_bf, WoutT, bout, CC, nullptr, query, attn_bf, ROWS, CC, CC, 2);
    // 6. h = LN(attnres) -> bf16
    ln_bf_kernel<<<ROWS, blk, 0, stream>>>(attn_bf, ffn_g, ffn_b, h_bf);
    // 7. h1 = gelu(h @ W1 + b1) -> bf16 (N=192)
    gemm64<<<dim3(3, ROWS / 64), blk, 0, stream>>>(
        h_bf, W1T, b1, HID, nullptr, nullptr, h1_bf, ROWS, CC, HID, 1 | 2);
    // 8. out = attnres + h1 @ W2 + b2 (K=192, f32 out, bf16 res)
    gemm64<<<dim3(12, ROWS / 64), blk, 0, stream>>>(
        h1_bf, W2T, b2, CC, nullptr, attn_bf, out, ROWS, HID, CC, 4);
}